// Round 9
// baseline (566.126 us; speedup 1.0000x reference)
//
#include <hip/hip_runtime.h>
#include <stdint.h>

// VQ-VAE forward on MI355X — round 9 (= round 8 design, compile-fixed).
// d_out (fp32): out[4194304] | loss[1] | perplexity[1] | idx_as_float[16384]
//
// SINGLE fused dispatch: 1024 blocks x 256 thr, __launch_bounds__(256,4),
// 36.9KB LDS -> exactly 4 blocks/CU = all 1024 co-resident (no block retires
// before the barriers, so packing is guaranteed). Two device-scope grid
// barriers separate:
//   P1: codebook pack+swizzle+hw (8 rows/blk), z->zfrag A-frag layout via LDS
//       transpose (16 rows/blk), counts/loss init.
//   P2: gemm (r6/r7 verbatim): 8 XCD-pinned splits, dbuf LDS global_load_lds,
//       packed-key top-2 per split.
//   P3: finish (16 rows/blk): prune by approx key, fp64 rescore -> exact idx,
//       counts, loss, gather -> out; last-block ticket computes perplexity+loss.
// Fix vs r8: s_cand declared as int4 (*)[8] (HIP_vector_type has no operator[]
// so the flat-int4* 2D indexing didn't compile); (void)hipMemsetAsync.

#define M_TOTAL 16384
#define N_CODES 8192
#define KDIM    256
#define SPATIAL 4096
#define NSPLIT  8
#define CODES_PER_SPLIT  1024
#define CHUNKS_PER_SPLIT 32
#define CHUNK_HALFS      8192      // 32 codes * 256 dims
#define CHUNK_BYTES      16384
#define GRID_BLOCKS      1024

typedef _Float16 v8hf __attribute__((ext_vector_type(8)));
typedef _Float16 v4hf __attribute__((ext_vector_type(4)));
typedef float    v4f  __attribute__((ext_vector_type(4)));

// ---------------------------------------------------------------- top-2 MAX merge
__device__ __forceinline__ void top2max_merge(uint32_t& v1, int& i1, uint32_t& v2, int& i2,
                                              uint32_t o1, int oi1, uint32_t o2, int oi2) {
    bool ob = (o1 > v1) || (o1 == v1 && oi1 < i1);
    uint32_t n1v, n2v; int n1i, n2i;
    if (ob) {
        bool t2 = (v1 > o2) || (v1 == o2 && i1 < oi2);
        n1v = o1; n1i = oi1;
        n2v = t2 ? v1 : o2; n2i = t2 ? i1 : oi2;
    } else {
        bool t2 = (o1 > v2) || (o1 == v2 && oi1 < i2);
        n1v = v1; n1i = i1;
        n2v = t2 ? o1 : v2; n2i = t2 ? oi1 : i2;
    }
    v1 = n1v; i1 = n1i; v2 = n2v; i2 = n2i;
}

// ---------------------------------------------------------------- grid barrier
// All 1024 blocks co-resident; device-scope release (threadfence) + ticket +
// acquire spin. Distinct counter per barrier.
__device__ __forceinline__ void grid_barrier(int* sem) {
    __syncthreads();
    if (threadIdx.x == 0) {
        __threadfence();   // device-scope release of all prior writes
        __hip_atomic_fetch_add(sem, 1, __ATOMIC_ACQ_REL, __HIP_MEMORY_SCOPE_AGENT);
        while (__hip_atomic_load(sem, __ATOMIC_ACQUIRE, __HIP_MEMORY_SCOPE_AGENT)
               < GRID_BLOCKS) {
            __builtin_amdgcn_s_sleep(2);
        }
    }
    __syncthreads();
}

// ---------------------------------------------------------------- fused kernel
__global__ __launch_bounds__(256, 4) void vq_fused_kernel(
    const float* __restrict__ z, const float* __restrict__ w,
    _Float16* __restrict__ wpk, float* __restrict__ hw_arr,
    _Float16* __restrict__ zfrag, int4* __restrict__ candbuf,
    int* __restrict__ counts, double* __restrict__ loss_acc,
    int* __restrict__ ctrl,                      // [0],[1]: barriers  [2]: ticket
    float* __restrict__ out, float* __restrict__ out_scalars,
    float* __restrict__ out_idx_f)
{
    __shared__ __align__(16) char smem[36864];   // 36KB union -> 4 blocks/CU

    const int bid = blockIdx.x;
    const int tid = threadIdx.x;
    const int wave = tid >> 6;
    const int lane = tid & 63;

    // ================= PHASE 1: prep =================
    {
        // ---- z -> zfrag (16 rows = one g16 group per block) via LDS transpose ----
        _Float16 (*tile)[18] = (_Float16 (*)[18])smem;     // [256][18] = 9.2KB
        const int i0z = bid * 16;
        const int bz  = i0z >> 12;
        const int s0z = i0z & (SPATIAL - 1);
        const float* zb = z + ((size_t)bz << 20) + s0z;
#pragma unroll
        for (int i = 0; i < 16; i++) {
            const int e = i * 256 + tid;
            const int k = e >> 4, rr = e & 15;
            tile[k][rr] = (_Float16)zb[((size_t)k << 12) + rr];
        }

        // ---- codebook: 8 rows/block, 2 per wave (no LDS) ----
#pragma unroll
        for (int rep = 0; rep < 2; rep++) {
            const int n = bid * 8 + wave * 2 + rep;
            v4f v = ((const v4f*)(w + (size_t)n * KDIM))[lane];
            v4hf hv;
            float s = 0.0f;
#pragma unroll
            for (int j = 0; j < 4; j++) {
                float f = v[j];
                s += f * f;
                hv[j] = (_Float16)f;
            }
            const int chunk = n >> 5;
            const int row   = n & 31;
            const int gg    = (lane >> 1) ^ (n & 7);       // 16B-granule swizzle
            size_t off = (size_t)chunk * CHUNK_HALFS + row * 256 + gg * 8 + (lane & 1) * 4;
            *(v4hf*)(wpk + off) = hv;
#pragma unroll
            for (int o = 32; o >= 1; o >>= 1) s += __shfl_xor(s, o);
            if (lane == 0) hw_arr[n] = 1024.0f - 0.5f * s; // acc = hw + dot > 0
        }
        if (tid < 8) counts[bid * 8 + tid] = 0;
        if (bid == 0 && tid == 0) *loss_acc = 0.0;

        __syncthreads();
        // ---- zfrag stores: 512 v8hf slots, 2 per thread ----
#pragma unroll
        for (int rep = 0; rep < 2; rep++) {
            const int sidx = rep * 256 + tid;
            const int ks = sidx >> 6, l2 = sidx & 63;
            const int r2 = l2 & 15, q2 = l2 >> 4;
            v8hf o;
#pragma unroll
            for (int j = 0; j < 8; j++)
                o[j] = tile[ks * 32 + q2 * 8 + j][r2];
            *(v8hf*)(zfrag + ((size_t)(bid * 8 + ks) * 64 + l2) * 8) = o;
        }
    }

    grid_barrier(&ctrl[0]);

    // ================= PHASE 2: gemm (r6/r7 verbatim) =================
    {
        _Float16* lds = (_Float16*)smem;                   // [2][8192] = 32KB
        float* hw_lds = (float*)(smem + 32768);            // [1024] = 4KB

        const int split = bid & 7;
        const int rb    = bid >> 3;
        const int i0    = rb * 128;
        const int r     = lane & 15;
        const int q     = lane >> 4;

        const char* wsplit = (const char*)wpk + (size_t)split * (CODES_PER_SPLIT * KDIM * 2);
        auto stage = [&](int chunk, int buf) {
            const char* gb = wsplit + (size_t)chunk * CHUNK_BYTES + tid * 16;
            _Float16* lb = lds + buf * CHUNK_HALFS + tid * 8;
#pragma unroll
            for (int j = 0; j < 4; j++) {
                __builtin_amdgcn_global_load_lds(
                    (const __attribute__((address_space(1))) void*)(gb + j * 4096),
                    (__attribute__((address_space(3))) void*)(lb + j * 2048), 16, 0, 0);
            }
        };
        stage(0, 0);

        {
            v4f h = *(const v4f*)(hw_arr + split * CODES_PER_SPLIT + tid * 4);
            *(v4f*)&hw_lds[tid * 4] = h;
        }

        v8hf a[2][8];
        {
            const int g16 = (i0 + wave * 32) >> 4;
#pragma unroll
            for (int mt = 0; mt < 2; mt++) {
#pragma unroll
                for (int ks = 0; ks < 8; ks++)
                    a[mt][ks] = *(const v8hf*)(zfrag +
                        ((size_t)((g16 + mt) * 8 + ks) * 64 + lane) * 8);
            }
        }

        uint32_t k1[2][4], k2[2][4];
#pragma unroll
        for (int mt = 0; mt < 2; mt++)
#pragma unroll
        for (int g = 0; g < 4; g++) { k1[mt][g] = 0u; k2[mt][g] = 0u; }

        const int swz = r & 7;
        __syncthreads();   // stage(0) + hw_lds visible

#pragma unroll 1
        for (int it = 0; it < CHUNKS_PER_SPLIT; it++) {
            const int buf = it & 1;
            if (it + 1 < CHUNKS_PER_SPLIT) stage(it + 1, buf ^ 1);

            const float hw0 = hw_lds[it * 32 + r];
            const float hw1 = hw_lds[it * 32 + 16 + r];
            v4f acc[2][2];
#pragma unroll
            for (int mt = 0; mt < 2; mt++) {
                acc[mt][0] = (v4f){hw0, hw0, hw0, hw0};
                acc[mt][1] = (v4f){hw1, hw1, hw1, hw1};
            }
            const _Float16* L = lds + buf * CHUNK_HALFS;
#pragma unroll
            for (int st = 0; st < 2; st++) {
                const int rowoff = (st * 16 + r) * 256;
#pragma unroll
                for (int ks = 0; ks < 8; ks++) {
                    const int gran = ((ks << 2) | q) ^ swz;
                    v8hf bh = *(const v8hf*)(L + rowoff + (gran << 3));
#pragma unroll
                    for (int mt = 0; mt < 2; mt++)
                        acc[mt][st] = __builtin_amdgcn_mfma_f32_16x16x32_f16(a[mt][ks], bh, acc[mt][st], 0, 0, 0);
                }
            }
#pragma unroll
            for (int st = 0; st < 2; st++) {
                const uint32_t tag = (uint32_t)(it * 2 + st);
#pragma unroll
                for (int mt = 0; mt < 2; mt++)
#pragma unroll
                for (int g = 0; g < 4; g++) {
                    uint32_t key = (__float_as_uint(acc[mt][st][g]) & 0xFFFFFFC0u) | tag;
                    uint32_t o1 = k1[mt][g], o2 = k2[mt][g];
                    uint32_t hi = key > o2 ? key : o2;
                    k2[mt][g] = hi < o1 ? hi : o1;      // med3(key, k1, k2)
                    k1[mt][g] = key > o1 ? key : o1;
                }
            }
            __syncthreads();
        }

        const int nsbase = split * CODES_PER_SPLIT + r;
#pragma unroll
        for (int mt = 0; mt < 2; mt++) {
#pragma unroll
            for (int g = 0; g < 4; g++) {
                uint32_t K1 = k1[mt][g], K2 = k2[mt][g];
                int n1 = nsbase + (int)((K1 & 63u) << 4);
                int n2 = nsbase + (int)((K2 & 63u) << 4);
#pragma unroll
                for (int off = 1; off < 16; off <<= 1) {
                    uint32_t o1 = __shfl_xor(K1, off);
                    int     on1 = __shfl_xor(n1, off);
                    uint32_t o2 = __shfl_xor(K2, off);
                    int     on2 = __shfl_xor(n2, off);
                    top2max_merge(K1, n1, K2, n2, o1, on1, o2, on2);
                }
                if (r == 0) {
                    const int row = i0 + wave * 32 + mt * 16 + q * 4 + g;
                    candbuf[(size_t)row * 8 + split] = make_int4((int)K1, n1, (int)K2, n2);
                }
            }
        }
    }

    grid_barrier(&ctrl[1]);

    // ================= PHASE 3: finish (16 rows/block) =================
    {
        int4 (*s_cand)[8] = (int4 (*)[8])smem;             // [16][8] = 2KB
        float (*s_zw)[257] = (float (*)[257])(smem + 2048);// [16][257] = 16.4KB
        int*    s_fi  = (int*)(smem + 2048 + 16448);       // 64B
        double* s_red = (double*)(smem + 2048 + 16448 + 64);
        int*    s_last = (int*)(smem + 2048 + 16448 + 64 + 32);

        const int i0 = bid * 16;
        const int b  = i0 >> 12;
        const int s0 = i0 & (SPATIAL - 1);
        const int t  = tid;

        if (t < 128) s_cand[t >> 3][t & 7] = candbuf[(size_t)(i0 + (t >> 3)) * 8 + (t & 7)];

        for (int e = t; e < 16 * KDIM; e += 256) {         // z tile (fp32, exact)
            const int c = e >> 4, rr = e & 15;
            s_zw[rr][c] = z[((size_t)b << 20) + ((size_t)c << 12) + s0 + rr];
        }
        __syncthreads();

        const int row = t >> 4, seg = t & 15;              // 16 thr/row, 16 dims each
        float zs[16];
#pragma unroll
        for (int j = 0; j < 16; j++) zs[j] = s_zw[row][seg * 16 + j];

        float da[16];
        float dmin_a = 3.4e38f;
#pragma unroll
        for (int sp = 0; sp < 8; sp++) {
            int4 c = s_cand[row][sp];
            da[sp * 2]     = 2048.0f - 2.0f * __uint_as_float((uint32_t)c.x & 0xFFFFFFC0u);
            da[sp * 2 + 1] = 2048.0f - 2.0f * __uint_as_float((uint32_t)c.z & 0xFFFFFFC0u);
            dmin_a = fminf(dmin_a, fminf(da[sp * 2], da[sp * 2 + 1]));
        }
        const float cutoff = dmin_a + 0.5f;

        double dbest = 1e300; int nbest = 0x7fffffff;
#pragma unroll 1
        for (int c = 0; c < 16; c++) {
            if (da[c] > cutoff) continue;
            int4 cc = s_cand[row][c >> 1];
            const int n = (c & 1) ? cc.w : cc.y;
            const float* wr = w + (size_t)n * KDIM + seg * 16;
            double d = 0.0;
#pragma unroll
            for (int j = 0; j < 16; j++) {
                double df = (double)zs[j] - (double)wr[j];
                d += df * df;
            }
#pragma unroll
            for (int o = 1; o < 16; o <<= 1) d += __shfl_xor(d, o);
            if (d < dbest || (d == dbest && n < nbest)) { dbest = d; nbest = n; }
        }

        double lsum = 0.0;
        if (seg == 0) {
            s_fi[row] = nbest;
            out_idx_f[i0 + row] = (float)nbest;
            atomicAdd(&counts[nbest], 1);
            lsum = dbest;
        }
#pragma unroll
        for (int o = 1; o < 64; o <<= 1) lsum += __shfl_xor(lsum, o);
        if ((t & 63) == 0) s_red[t >> 6] = lsum;
        __syncthreads();
        if (t == 0) atomicAdd(loss_acc, s_red[0] + s_red[1] + s_red[2] + s_red[3]);

        // gather weight[fi] -> LDS (reuse s_zw) -> transposed coalesced write
        for (int e = t; e < 16 * KDIM; e += 256) {
            const int rr = e >> 8, c = e & 255;
            s_zw[rr][c] = w[(size_t)s_fi[rr] * KDIM + c];
        }
        __syncthreads();
        const int m = t & 15, c0 = t >> 4;
        const size_t obase = ((size_t)b << 20) + (size_t)(s0 + m);
        for (int c = c0; c < KDIM; c += 16)
            out[obase + ((size_t)c << 12)] = s_zw[m][c];

        // ---- last-block finalize ----
        if (t == 0) {
            __threadfence();
            int old = __hip_atomic_fetch_add(&ctrl[2], 1, __ATOMIC_ACQ_REL,
                                             __HIP_MEMORY_SCOPE_AGENT);
            *s_last = (old == GRID_BLOCKS - 1);
        }
        __syncthreads();
        if (*s_last) {
            double s = 0.0;
            for (int n = t; n < N_CODES; n += 256) {
                int c = __hip_atomic_load(&counts[n], __ATOMIC_RELAXED,
                                          __HIP_MEMORY_SCOPE_AGENT);
                double p = (double)c / (double)M_TOTAL;
                s -= p * log(p + 1e-10);
            }
#pragma unroll
            for (int o = 32; o >= 1; o >>= 1) s += __shfl_xor(s, o);
            if ((t & 63) == 0) s_red[t >> 6] = s;
            __syncthreads();
            if (t == 0) {
                double tot = s_red[0] + s_red[1] + s_red[2] + s_red[3];
                double l = __hip_atomic_load(loss_acc, __ATOMIC_RELAXED,
                                             __HIP_MEMORY_SCOPE_AGENT);
                out_scalars[0] = (float)(0.25 * l / (double)(M_TOTAL * KDIM));
                out_scalars[1] = (float)exp(tot);
            }
        }
    }
}

// ---------------------------------------------------------------- launch
extern "C" void kernel_launch(void* const* d_in, const int* in_sizes, int n_in,
                              void* d_out, int out_size, void* d_ws, size_t ws_size,
                              hipStream_t stream) {
    const float* z      = (const float*)d_in[0];   // 4*256*16*16*16 = 16.8 MB
    const float* weight = (const float*)d_in[1];   // 8192*256 = 8.4 MB
    float* out = (float*)d_out;

    size_t off = 0;
    auto carve = [&](size_t bytes) {
        void* p = (char*)d_ws + off;
        off += (bytes + 255) & ~(size_t)255;
        return p;
    };
    _Float16* wpk     = (_Float16*)carve((size_t)N_CODES * KDIM * 2);   // 4 MB
    float*    hw_arr  = (float*)   carve((size_t)N_CODES * 4);
    _Float16* zfrag   = (_Float16*)carve((size_t)M_TOTAL * KDIM * 2);   // 8 MB
    int4*     candbuf = (int4*)    carve((size_t)M_TOTAL * 8 * 16);     // 2 MB
    int*      counts  = (int*)     carve((size_t)N_CODES * 4);
    double*   lossac  = (double*)  carve(16);
    int*      ctrl    = (int*)     carve(256);

    float* out_scalars = out + (size_t)4 * KDIM * SPATIAL;   // [loss, perplexity]
    float* out_idx_f   = out_scalars + 2;                    // 16384 idx as float

    (void)hipMemsetAsync(ctrl, 0, 256, stream);              // barrier/ticket zero
    vq_fused_kernel<<<dim3(GRID_BLOCKS), dim3(256), 0, stream>>>(
        z, weight, wpk, hw_arr, zfrag, candbuf, counts, lossac, ctrl,
        out, out_scalars, out_idx_f);
}